// Round 1
// baseline (133179.456 us; speedup 1.0000x reference)
//
#include <hip/hip_runtime.h>

#define T_STEPS 32768
#define NWG 32        // workgroups per LSTM
#define THREADS 256

typedef unsigned int uint32;

// ws layout:
// [0,   256)  : flags, 64 uint (32 per lstm)
// [256, 8448) : hbuf, 2 lstm * 2 buffers * 512 floats

__global__ __launch_bounds__(THREADS, 1)
void lstm_persistent(const float* __restrict__ sa,
                     const float* __restrict__ W_ih1, const float* __restrict__ W_hh1,
                     const float* __restrict__ b_ih1, const float* __restrict__ b_hh1,
                     const float* __restrict__ W_ih2, const float* __restrict__ W_hh2,
                     const float* __restrict__ b_ih2, const float* __restrict__ b_hh2,
                     const float* __restrict__ W_xyz, const float* __restrict__ W_zeta,
                     const float* __restrict__ W_uvw, const float* __restrict__ W_pqr,
                     float* __restrict__ out, uint32* __restrict__ flags,
                     float* __restrict__ hbuf)
{
    const int blk  = blockIdx.x;
    const int lstm = blk >> 5;       // 0 or 1
    const int w    = blk & 31;       // WG index within its LSTM
    const int tid  = threadIdx.x;
    const int wave = tid >> 6;
    const int lane = tid & 63;

    const float* W_ih = lstm ? W_ih2 : W_ih1;
    const float* W_hh = lstm ? W_hh2 : W_hh1;
    const float* b_ih = lstm ? b_ih2 : b_ih1;
    const float* b_hh = lstm ? b_hh2 : b_hh1;
    const float* W_a  = lstm ? W_zeta : W_xyz;  // -> out cols 3*lstm + {0,1,2}
    const float* W_b  = lstm ? W_pqr  : W_uvw;  // -> out cols 6 + 3*lstm + {0,1,2}

    uint32* flg = flags + lstm * 32;
    float*  hb  = hbuf  + lstm * 1024;   // 2 buffers x 512

    __shared__ float h_lds[512];
    __shared__ float part_lds[64 * 5];   // [row][wave], stride 5 to dodge bank conflicts
    __shared__ float wih_lds[64 * 19];

    // local gate-row r = lane: gate g = r>>4, hidden jloc = r&15
    const int r    = lane;
    const int jloc = r & 15;
    const int grow = ((r >> 4) << 9) + (w << 4) + jloc;   // global gate row (0..2047)

    // ---- one-time setup ----
    // W_hh slice: 128 weights per thread, kept in VGPRs
    float wreg[128];
    {
        const float* wp = W_hh + (size_t)grow * 512 + wave * 128;
        #pragma unroll
        for (int k = 0; k < 128; ++k) wreg[k] = wp[k];
    }
    // W_ih rows for this WG into LDS
    for (int idx = tid; idx < 64 * 19; idx += THREADS) {
        int rr = idx / 19, kk = idx - rr * 19;
        int gr = ((rr >> 4) << 9) + (w << 4) + (rr & 15);
        wih_lds[idx] = W_ih[gr * 19 + kk];
    }
    const float bsum = b_ih[grow] + b_hh[grow];

    // projection weight slices (wave 0, lanes 0..15 use them)
    float pj[6];
    #pragma unroll
    for (int o = 0; o < 6; ++o) pj[o] = 0.f;
    if (wave == 0) {
        #pragma unroll
        for (int o = 0; o < 3; ++o) {
            pj[o]     = W_a[o * 512 + (w << 4) + jloc];
            pj[o + 3] = W_b[o * 512 + (w << 4) + jloc];
        }
    }

    float c_reg = 0.0f;
    __syncthreads();

    for (int t = 0; t < T_STEPS; ++t) {
        // ---- 1. wait for h_{t-1}, gather into LDS ----
        if (t > 0) {
            if (wave == 0) {
                uint32 v;
                do {
                    v = __hip_atomic_load(&flg[lane & 31], __ATOMIC_ACQUIRE,
                                          __HIP_MEMORY_SCOPE_AGENT);
                } while (__any((int)(v < (uint32)t)));
            }
            __syncthreads();
            const float* src = hb + ((t - 1) & 1) * 512;
            h_lds[tid]       = __hip_atomic_load(&src[tid],       __ATOMIC_RELAXED,
                                                 __HIP_MEMORY_SCOPE_AGENT);
            h_lds[tid + 256] = __hip_atomic_load(&src[tid + 256], __ATOMIC_RELAXED,
                                                 __HIP_MEMORY_SCOPE_AGENT);
        } else {
            h_lds[tid] = 0.f;
            h_lds[tid + 256] = 0.f;
        }
        __syncthreads();

        // ---- 2. mat-vec partial: row r, columns [wave*128, wave*128+128) ----
        float a0 = 0.f, a1 = 0.f, a2 = 0.f, a3 = 0.f;
        const float* hp = &h_lds[wave * 128];
        #pragma unroll
        for (int k = 0; k < 128; k += 4) {
            a0 += wreg[k]     * hp[k];
            a1 += wreg[k + 1] * hp[k + 1];
            a2 += wreg[k + 2] * hp[k + 2];
            a3 += wreg[k + 3] * hp[k + 3];
        }
        part_lds[r * 5 + wave] = (a0 + a1) + (a2 + a3);
        __syncthreads();

        // ---- 3. gate assembly + cell update (wave 0 only) ----
        if (wave == 0) {
            float gsum = part_lds[r * 5] + part_lds[r * 5 + 1] +
                         part_lds[r * 5 + 2] + part_lds[r * 5 + 3];
            // gx on the fly: b_ih + b_hh + sum_k sa[t,k] * W_ih[grow,k]
            const float* sarow = sa + (size_t)t * 19;
            float myv = (lane < 19) ? sarow[lane] : 0.f;
            float pre = gsum + bsum;
            #pragma unroll
            for (int k = 0; k < 19; ++k)
                pre += __shfl(myv, k) * wih_lds[r * 19 + k];

            const int g = r >> 4;
            float act = (g == 2) ? tanhf(pre) : 1.f / (1.f + expf(-pre));

            // rows: i at lane jloc, f at 16+jloc, g at 32+jloc, o at 48+jloc
            float i_v = __shfl(act, jloc);
            float f_v = __shfl(act, 16 + jloc);
            float g_v = __shfl(act, 32 + jloc);
            float o_v = __shfl(act, 48 + jloc);

            float hn = 0.f;
            if (r < 16) {
                c_reg = f_v * c_reg + i_v * g_v;
                hn    = o_v * tanhf(c_reg);
                __hip_atomic_store(&hb[(t & 1) * 512 + (w << 4) + jloc], hn,
                                   __ATOMIC_RELAXED, __HIP_MEMORY_SCOPE_AGENT);
            }
            // publish flag (release orders the 16 h stores above)
            if (lane == 0)
                __hip_atomic_store(&flg[w], (uint32)(t + 1),
                                   __ATOMIC_RELEASE, __HIP_MEMORY_SCOPE_AGENT);

            // ---- 4. fused output projections (off critical path) ----
            if (r < 16) {
                #pragma unroll
                for (int o = 0; o < 6; ++o) {
                    float v = hn * pj[o];
                    v += __shfl_xor(v, 1);
                    v += __shfl_xor(v, 2);
                    v += __shfl_xor(v, 4);
                    v += __shfl_xor(v, 8);
                    if (jloc == 0) {
                        int col = (o < 3) ? (3 * lstm + o) : (6 + 3 * lstm + (o - 3));
                        atomicAdd(&out[(size_t)t * 12 + col], v);
                    }
                }
            }
        }
    }
}

__global__ void init_out(const float* __restrict__ b_xyz, const float* __restrict__ b_zeta,
                         const float* __restrict__ b_uvw, const float* __restrict__ b_pqr,
                         float* __restrict__ out)
{
    int idx = blockIdx.x * blockDim.x + threadIdx.x;
    if (idx < T_STEPS * 12) {
        int o = idx % 12;
        float v;
        if (o < 3)      v = b_xyz[o];
        else if (o < 6) v = b_zeta[o - 3];
        else if (o < 9) v = b_uvw[o - 6];
        else            v = b_pqr[o - 9];
        out[idx] = v;
    }
}

extern "C" void kernel_launch(void* const* d_in, const int* in_sizes, int n_in,
                              void* d_out, int out_size, void* d_ws, size_t ws_size,
                              hipStream_t stream)
{
    const float* sa    = (const float*)d_in[0];
    const float* W_ih1 = (const float*)d_in[1];
    const float* W_hh1 = (const float*)d_in[2];
    const float* b_ih1 = (const float*)d_in[3];
    const float* b_hh1 = (const float*)d_in[4];
    const float* W_ih2 = (const float*)d_in[5];
    const float* W_hh2 = (const float*)d_in[6];
    const float* b_ih2 = (const float*)d_in[7];
    const float* b_hh2 = (const float*)d_in[8];
    const float* W_xyz = (const float*)d_in[9];
    const float* b_xyz = (const float*)d_in[10];
    const float* W_zeta= (const float*)d_in[11];
    const float* b_zeta= (const float*)d_in[12];
    const float* W_uvw = (const float*)d_in[13];
    const float* b_uvw = (const float*)d_in[14];
    const float* W_pqr = (const float*)d_in[15];
    const float* b_pqr = (const float*)d_in[16];

    float*  out   = (float*)d_out;
    uint32* flags = (uint32*)d_ws;
    float*  hbuf  = (float*)((char*)d_ws + 256);

    // zero flags + h buffers (must happen every call; graph-replayed)
    hipMemsetAsync(d_ws, 0, 256 + 2 * 2 * 512 * sizeof(float), stream);
    // initialize out with biases; persistent kernel atomicAdds partial dots
    init_out<<<(T_STEPS * 12 + 255) / 256, 256, 0, stream>>>(b_xyz, b_zeta, b_uvw, b_pqr, out);

    lstm_persistent<<<2 * NWG, THREADS, 0, stream>>>(
        sa, W_ih1, W_hh1, b_ih1, b_hh1, W_ih2, W_hh2, b_ih2, b_hh2,
        W_xyz, W_zeta, W_uvw, W_pqr, out, flags, hbuf);
}

// Round 2
// 94561.340 us; speedup vs baseline: 1.4084x; 1.4084x over previous
//
#include <hip/hip_runtime.h>

#define T_STEPS 32768
#define NWG 32        // workgroups per LSTM
#define THREADS 256

typedef unsigned int uint32;
typedef unsigned long long ull;

// ws layout: hbuf = ull[2 lstm][2 buffers][512]  (16 KB)
// each ull: low 32 = tag (t+1 for h produced at step t), high 32 = f32 bits of h

__device__ inline float fsig(float x) {
    return __builtin_amdgcn_rcpf(1.f + __expf(-x));
}
__device__ inline float ftanh(float x) {
    return 1.f - 2.f * __builtin_amdgcn_rcpf(1.f + __expf(2.f * x));
}

__global__ __launch_bounds__(THREADS, 1)
void lstm_persistent(const float* __restrict__ sa,
                     const float* __restrict__ W_ih1, const float* __restrict__ W_hh1,
                     const float* __restrict__ b_ih1, const float* __restrict__ b_hh1,
                     const float* __restrict__ W_ih2, const float* __restrict__ W_hh2,
                     const float* __restrict__ b_ih2, const float* __restrict__ b_hh2,
                     const float* __restrict__ W_xyz, const float* __restrict__ W_zeta,
                     const float* __restrict__ W_uvw, const float* __restrict__ W_pqr,
                     float* __restrict__ out, ull* __restrict__ hbuf)
{
    const int blk  = blockIdx.x;
    const int lstm = blk >> 5;       // 0 or 1
    const int w    = blk & 31;       // WG index within its LSTM
    const int tid  = threadIdx.x;
    const int wave = tid >> 6;
    const int lane = tid & 63;

    const float* W_ih = lstm ? W_ih2 : W_ih1;
    const float* W_hh = lstm ? W_hh2 : W_hh1;
    const float* b_ih = lstm ? b_ih2 : b_ih1;
    const float* b_hh = lstm ? b_hh2 : b_hh1;
    const float* W_a  = lstm ? W_zeta : W_xyz;  // -> out cols 3*lstm + {0,1,2}
    const float* W_b  = lstm ? W_pqr  : W_uvw;  // -> out cols 6 + 3*lstm + {0,1,2}

    ull* hb = hbuf + lstm * 1024;    // 2 buffers x 512

    __shared__ __align__(16) float h_lds[512];
    __shared__ float part_lds[64 * 5];   // [row][wave], stride 5
    __shared__ float wih_lds[64 * 19];

    // gate-row r = lane: gate g = r>>4, hidden jloc = r&15
    const int r    = lane;
    const int jloc = r & 15;
    const int grow = ((r >> 4) << 9) + (w << 4) + jloc;   // global gate row

    // ---- one-time setup ----
    // W_hh slice: 32 float4 = 128 weights per thread, in VGPRs
    float4 wreg[32];
    {
        const float4* wp4 = (const float4*)(W_hh + (size_t)grow * 512 + wave * 128);
        #pragma unroll
        for (int k = 0; k < 32; ++k) wreg[k] = wp4[k];
    }
    for (int idx = tid; idx < 64 * 19; idx += THREADS) {
        int rr = idx / 19, kk = idx - rr * 19;
        int gr = ((rr >> 4) << 9) + (w << 4) + (rr & 15);
        wih_lds[idx] = W_ih[gr * 19 + kk];
    }
    const float bsum = b_ih[grow] + b_hh[grow];

    // projection weight slices live in WAVE 1 (lanes 0..15)
    float pj[6];
    #pragma unroll
    for (int o = 0; o < 6; ++o) pj[o] = 0.f;
    if (wave == 1 && lane < 16) {
        #pragma unroll
        for (int o = 0; o < 3; ++o) {
            pj[o]     = W_a[o * 512 + (w << 4) + lane];
            pj[o + 3] = W_b[o * 512 + (w << 4) + lane];
        }
    }

    float c_reg = 0.0f;
    const int e0 = tid, e1 = tid + 256;
    __syncthreads();

    for (int t = 0; t < T_STEPS; ++t) {
        // ---- 0. prefetch sa row (independent of h) ----
        float sav = 0.f;
        if (wave == 0 && lane < 19) sav = sa[(size_t)t * 19 + lane];

        // ---- 1. poll-and-gather h_{t-1} (tag == t) ----
        if (t > 0) {
            const ull* src = hb + ((t - 1) & 1) * 512;
            const uint32 tag = (uint32)t;
            ull v0 = 0, v1 = 0;
            bool d0 = false, d1 = false;
            while (!(d0 && d1)) {
                if (!d0) {
                    v0 = __hip_atomic_load(&src[e0], __ATOMIC_RELAXED,
                                           __HIP_MEMORY_SCOPE_AGENT);
                    d0 = ((uint32)v0 == tag);
                }
                if (!d1) {
                    v1 = __hip_atomic_load(&src[e1], __ATOMIC_RELAXED,
                                           __HIP_MEMORY_SCOPE_AGENT);
                    d1 = ((uint32)v1 == tag);
                }
            }
            h_lds[e0] = __uint_as_float((uint32)(v0 >> 32));
            h_lds[e1] = __uint_as_float((uint32)(v1 >> 32));
        } else {
            h_lds[e0] = 0.f;
            h_lds[e1] = 0.f;
        }
        __syncthreads();

        // wave1 snapshots its own-WG slice of h_{t-1} for the deferred projection
        float hprev = 0.f;
        if (wave == 1 && lane < 16) hprev = h_lds[(w << 4) + lane];

        // ---- 2. mat-vec partial: row r, cols [wave*128, wave*128+128) ----
        {
            const float4* hp4 = (const float4*)(h_lds + wave * 128);
            float ax = 0.f, ay = 0.f, az = 0.f, aw = 0.f;
            #pragma unroll
            for (int k = 0; k < 32; ++k) {
                float4 wv = wreg[k];
                float4 hv = hp4[k];
                ax = fmaf(wv.x, hv.x, ax);
                ay = fmaf(wv.y, hv.y, ay);
                az = fmaf(wv.z, hv.z, az);
                aw = fmaf(wv.w, hv.w, aw);
            }
            part_lds[r * 5 + wave] = (ax + ay) + (az + aw);
        }
        __syncthreads();

        // ---- 3. gate assembly + cell update (wave 0) ----
        if (wave == 0) {
            float pre = part_lds[r * 5] + part_lds[r * 5 + 1] +
                        part_lds[r * 5 + 2] + part_lds[r * 5 + 3] + bsum;
            #pragma unroll
            for (int k = 0; k < 19; ++k)
                pre += __shfl(sav, k) * wih_lds[r * 19 + k];

            const int g = r >> 4;
            float act = (g == 2) ? ftanh(pre) : fsig(pre);

            float i_v = __shfl(act, jloc);
            float f_v = __shfl(act, 16 + jloc);
            float g_v = __shfl(act, 32 + jloc);
            float o_v = __shfl(act, 48 + jloc);

            if (r < 16) {
                c_reg = f_v * c_reg + i_v * g_v;
                float hn = o_v * ftanh(c_reg);
                ull pk = ((ull)__float_as_uint(hn) << 32) | (ull)(uint32)(t + 1);
                __hip_atomic_store(&hb[(t & 1) * 512 + (w << 4) + jloc], pk,
                                   __ATOMIC_RELAXED, __HIP_MEMORY_SCOPE_AGENT);
            }
        }
        // ---- 4. deferred output projection for out[t-1] (wave 1, off path) ----
        else if (wave == 1 && lane < 16 && t > 0) {
            #pragma unroll
            for (int o = 0; o < 6; ++o) {
                float v = hprev * pj[o];
                v += __shfl_xor(v, 1);
                v += __shfl_xor(v, 2);
                v += __shfl_xor(v, 4);
                v += __shfl_xor(v, 8);
                if (lane == 0) {
                    int col = (o < 3) ? (3 * lstm + o) : (6 + 3 * lstm + (o - 3));
                    atomicAdd(&out[(size_t)(t - 1) * 12 + col], v);
                }
            }
        }
    }

    // ---- final projection for out[T-1] (wave 1 polls its own slice) ----
    if (wave == 1 && lane < 16) {
        const ull* src = hb + ((T_STEPS - 1) & 1) * 512;
        ull v;
        do {
            v = __hip_atomic_load(&src[(w << 4) + lane], __ATOMIC_RELAXED,
                                  __HIP_MEMORY_SCOPE_AGENT);
        } while ((uint32)v != (uint32)T_STEPS);
        float hl = __uint_as_float((uint32)(v >> 32));
        #pragma unroll
        for (int o = 0; o < 6; ++o) {
            float s = hl * pj[o];
            s += __shfl_xor(s, 1);
            s += __shfl_xor(s, 2);
            s += __shfl_xor(s, 4);
            s += __shfl_xor(s, 8);
            if (lane == 0) {
                int col = (o < 3) ? (3 * lstm + o) : (6 + 3 * lstm + (o - 3));
                atomicAdd(&out[(size_t)(T_STEPS - 1) * 12 + col], s);
            }
        }
    }
}

__global__ void init_out(const float* __restrict__ b_xyz, const float* __restrict__ b_zeta,
                         const float* __restrict__ b_uvw, const float* __restrict__ b_pqr,
                         float* __restrict__ out)
{
    int idx = blockIdx.x * blockDim.x + threadIdx.x;
    if (idx < T_STEPS * 12) {
        int o = idx % 12;
        float v;
        if (o < 3)      v = b_xyz[o];
        else if (o < 6) v = b_zeta[o - 3];
        else if (o < 9) v = b_uvw[o - 6];
        else            v = b_pqr[o - 9];
        out[idx] = v;
    }
}

extern "C" void kernel_launch(void* const* d_in, const int* in_sizes, int n_in,
                              void* d_out, int out_size, void* d_ws, size_t ws_size,
                              hipStream_t stream)
{
    const float* sa    = (const float*)d_in[0];
    const float* W_ih1 = (const float*)d_in[1];
    const float* W_hh1 = (const float*)d_in[2];
    const float* b_ih1 = (const float*)d_in[3];
    const float* b_hh1 = (const float*)d_in[4];
    const float* W_ih2 = (const float*)d_in[5];
    const float* W_hh2 = (const float*)d_in[6];
    const float* b_ih2 = (const float*)d_in[7];
    const float* b_hh2 = (const float*)d_in[8];
    const float* W_xyz = (const float*)d_in[9];
    const float* b_xyz = (const float*)d_in[10];
    const float* W_zeta= (const float*)d_in[11];
    const float* b_zeta= (const float*)d_in[12];
    const float* W_uvw = (const float*)d_in[13];
    const float* b_uvw = (const float*)d_in[14];
    const float* W_pqr = (const float*)d_in[15];
    const float* b_pqr = (const float*)d_in[16];

    float* out  = (float*)d_out;
    ull*   hbuf = (ull*)d_ws;

    // zero tag words every call (graph-replayed)
    hipMemsetAsync(d_ws, 0, 2 * 2 * 512 * sizeof(ull), stream);
    init_out<<<(T_STEPS * 12 + 255) / 256, 256, 0, stream>>>(b_xyz, b_zeta, b_uvw, b_pqr, out);

    lstm_persistent<<<2 * NWG, THREADS, 0, stream>>>(
        sa, W_ih1, W_hh1, b_ih1, b_hh1, W_ih2, W_hh2, b_ih2, b_hh2,
        W_xyz, W_zeta, W_uvw, W_pqr, out, hbuf);
}